// Round 12
// baseline (87.680 us; speedup 1.0000x reference)
//
#include <hip/hip_runtime.h>
#include <hip/hip_bf16.h>

#define S_DIM 128
#define R_DIM 256
#define CM    256
#define H_DIM 32
#define CZ    128

typedef short s8v   __attribute__((ext_vector_type(8)));   // 8 bf16 in 4 VGPRs
typedef float f32x4 __attribute__((ext_vector_type(4)));
typedef float f32x16 __attribute__((ext_vector_type(16)));
using bf16 = __hip_bfloat16;

static __device__ __forceinline__ unsigned short bf16_bits(float f) {
  return __builtin_bit_cast(unsigned short, __float2bfloat16(f));
}

static __device__ __forceinline__ void gload_lds16(const void* g, void* l) {
  __builtin_amdgcn_global_load_lds(
      (const __attribute__((address_space(1))) unsigned int*)g,
      (__attribute__((address_space(3))) unsigned int*)l, 16, 0, 0);
}

// ---------------------------------------------------------------------------
// Kernel 0 (prep, one launch):
//  blocks 0..63   : w_out [1024][128] fp32 -> wT2 bf16, 16x16x32 B-frag order:
//                   vec v = tb16*32 + ks; lane l elem e:
//                   t = tb16*16 + (l&15), k = ks*32 + (l>>4)*8 + e,
//                   w_out row = (k&31)*32 + (k>>5)
//  blocks 64..319 : rnorm[i][j] = 1/(sum_s mask1[s,i]*mask2[s,j] + 1e-3)
//  blocks 320..321: w1/w2 [256][32] fp32 -> wF bf16 in proj B-frag order
// ---------------------------------------------------------------------------
__global__ __launch_bounds__(256) void opm_prep(
    const float* __restrict__ w_out,
    const float* __restrict__ mask1, const float* __restrict__ mask2,
    const float* __restrict__ w1, const float* __restrict__ w2,
    bf16* __restrict__ wT2, float* __restrict__ rnorm, bf16* __restrict__ wF)
{
  const int b   = blockIdx.x;
  const int tid = threadIdx.x;
  if (b < 64) {
    const int vid  = b*256 + tid;         // 16384 lane-slots
    const int lane = vid & 63;
    const int vec  = vid >> 6;            // 0..255
    const int tb16 = vec >> 5;            // 0..7
    const int ks   = vec & 31;            // 0..31
    const int q    = lane >> 4;           // 0..3
    const int t    = tb16*16 + (lane & 15);
    unsigned int pk[4];
    #pragma unroll
    for (int ep = 0; ep < 4; ++ep) {
      const int k0 = ks*32 + q*8 + ep*2;
      const int k1 = k0 + 1;
      unsigned int v0 = bf16_bits(w_out[((k0 & 31)*32 + (k0 >> 5))*CZ + t]);
      unsigned int v1 = bf16_bits(w_out[((k1 & 31)*32 + (k1 >> 5))*CZ + t]);
      pk[ep] = v0 | (v1 << 16);
    }
    uint4 o = {pk[0], pk[1], pk[2], pk[3]};
    *reinterpret_cast<uint4*>((char*)wT2 + (size_t)vid*16) = o;
  } else if (b < 320) {
    const int i = b - 64;
    const int j = tid;
    float acc = 0.f;
    for (int s = 0; s < S_DIM; ++s)
      acc += mask1[(size_t)s*R_DIM + i] * mask2[(size_t)s*R_DIM + j];
    rnorm[i*R_DIM + j] = 1.0f / (acc + 1e-3f);
  } else {
    const int mat = b - 320;
    const float* __restrict__ w = mat ? w2 : w1;
    bf16* __restrict__ dst = wF + mat*8192;
    #pragma unroll
    for (int it = 0; it < 4; ++it) {
      const int vid  = it*256 + tid;
      const int nf   = vid >> 9;
      const int ks   = (vid >> 6) & 7;
      const int lane = vid & 63;
      const int h    = nf*16 + (lane & 15);
      unsigned int pk[4];
      #pragma unroll
      for (int ep = 0; ep < 4; ++ep) {
        const int c0 = ks*32 + (lane >> 4)*8 + ep*2;
        unsigned int lo = bf16_bits(w[c0*H_DIM + h]);
        unsigned int hi = bf16_bits(w[(c0 + 1)*H_DIM + h]);
        pk[ep] = lo | (hi << 16);
      }
      uint4 o = {pk[0], pk[1], pk[2], pk[3]};
      *reinterpret_cast<uint4*>((char*)dst + (size_t)vid*16) = o;
    }
  }
}

// ---------------------------------------------------------------------------
// Kernel 1 (proj): 1 wave per block, 16 rows (s0..s0+15, r) of one matrix.
// (Round-8 version, unchanged.)
// ---------------------------------------------------------------------------
__global__ __launch_bounds__(64) void opm_proj(
    const float* __restrict__ m1, const float* __restrict__ m2,
    const float* __restrict__ ln1w, const float* __restrict__ ln1b,
    const float* __restrict__ ln2w, const float* __restrict__ ln2b,
    const float* __restrict__ b1, const float* __restrict__ b2,
    const float* __restrict__ mask1, const float* __restrict__ mask2,
    const bf16* __restrict__ wF, bf16* __restrict__ aT, bf16* __restrict__ bT)
{
  __shared__ char xn[8192];   // [16 s][256 c] bf16, byte ^ ((s&7)<<4)

  const int mat = blockIdx.y;
  const float* __restrict__ m    = mat ? m2   : m1;
  const float* __restrict__ lnw  = mat ? ln2w : ln1w;
  const float* __restrict__ lnb  = mat ? ln2b : ln1b;
  const float* __restrict__ bias = mat ? b2   : b1;
  const float* __restrict__ mask = mat ? mask2 : mask1;
  const bf16* __restrict__ wf    = wF + mat*8192;
  bf16* __restrict__ dst         = mat ? bT   : aT;

  const int lane = threadIdx.x;
  const int g16  = lane >> 4;      // row-within-pass (= q later)
  const int c16  = lane & 15;      // 16B segment index (= row later)
  const int r    = blockIdx.x & 255;
  const int sb   = blockIdx.x >> 8;

  // ---- issue ALL global loads up front ----
  float4 x[4][4];                  // [pass][it]
  #pragma unroll
  for (int p = 0; p < 4; ++p) {
    const int s = sb*16 + p*4 + g16;
    const float4* __restrict__ src =
        reinterpret_cast<const float4*>(m + ((size_t)s*R_DIM + r)*CM);
    #pragma unroll
    for (int it = 0; it < 4; ++it)
      x[p][it] = src[c16 + it*16];
  }
  const float4* __restrict__ lnw4 = reinterpret_cast<const float4*>(lnw);
  const float4* __restrict__ lnb4 = reinterpret_cast<const float4*>(lnb);
  float4 lw[4], lb[4];
  #pragma unroll
  for (int it = 0; it < 4; ++it) {
    lw[it] = lnw4[c16 + it*16];
    lb[it] = lnb4[c16 + it*16];
  }
  float mk[4];
  #pragma unroll
  for (int rr = 0; rr < 4; ++rr)
    mk[rr] = mask[(size_t)(sb*16 + g16*4 + rr)*R_DIM + r];
  const float bv0 = bias[c16];
  const float bv1 = bias[16 + c16];

  // ---- 4 independent sum/sq + shfl-reduce chains ----
  float sum[4], sq[4];
  #pragma unroll
  for (int p = 0; p < 4; ++p) {
    float s0 = 0.f, s1 = 0.f;
    #pragma unroll
    for (int it = 0; it < 4; ++it) {
      const float4 v = x[p][it];
      s0 += v.x + v.y + v.z + v.w;
      s1 += v.x*v.x + v.y*v.y + v.z*v.z + v.w*v.w;
    }
    sum[p] = s0; sq[p] = s1;
  }
  #pragma unroll
  for (int off = 1; off < 16; off <<= 1) {
    #pragma unroll
    for (int p = 0; p < 4; ++p) {
      sum[p] += __shfl_xor(sum[p], off);
      sq[p]  += __shfl_xor(sq[p], off);
    }
  }
  float mu[4], rs[4];
  #pragma unroll
  for (int p = 0; p < 4; ++p) {
    mu[p] = sum[p] * (1.0f/CM);
    rs[p] = rsqrtf(sq[p] * (1.0f/CM) - mu[p]*mu[p] + 1e-5f);
  }

  // ---- ln affine -> bf16 -> LDS ----
  #pragma unroll
  for (int p = 0; p < 4; ++p) {
    const int row = p*4 + g16;
    #pragma unroll
    for (int it = 0; it < 4; ++it) {
      const float v0 = (x[p][it].x - mu[p])*rs[p]*lw[it].x + lb[it].x;
      const float v1 = (x[p][it].y - mu[p])*rs[p]*lw[it].y + lb[it].y;
      const float v2 = (x[p][it].z - mu[p])*rs[p]*lw[it].z + lb[it].z;
      const float v3 = (x[p][it].w - mu[p])*rs[p]*lw[it].w + lb[it].w;
      uint2 pk;
      pk.x = (unsigned)bf16_bits(v0) | ((unsigned)bf16_bits(v1) << 16);
      pk.y = (unsigned)bf16_bits(v2) | ((unsigned)bf16_bits(v3) << 16);
      int off = row*512 + c16*8 + it*128;
      off ^= (row & 7) << 4;
      *reinterpret_cast<uint2*>(xn + off) = pk;
    }
  }
  __syncthreads();

  // ---- MFMA: [16 s x 256 c] @ w[256 c x 32 h] ----
  const int row = c16;
  const int q   = g16;
  f32x4 z0 = {bv0, bv0, bv0, bv0};
  f32x4 z1 = {bv1, bv1, bv1, bv1};
  #pragma unroll
  for (int ks = 0; ks < 8; ++ks) {
    int off = row*512 + ks*64 + q*16;
    off ^= (row & 7) << 4;
    const s8v a  = *reinterpret_cast<const s8v*>(xn + off);
    const s8v w0 = *reinterpret_cast<const s8v*>((const char*)wf + (ks*64 + lane)*16);
    const s8v w1 = *reinterpret_cast<const s8v*>((const char*)wf + ((8 + ks)*64 + lane)*16);
    z0 = __builtin_amdgcn_mfma_f32_16x16x32_bf16(a, w0, z0, 0, 0, 0);
    z1 = __builtin_amdgcn_mfma_f32_16x16x32_bf16(a, w1, z1, 0, 0, 0);
  }

  unsigned int pa0 = (unsigned)bf16_bits(z0[0]*mk[0]) | ((unsigned)bf16_bits(z0[1]*mk[1]) << 16);
  unsigned int pa1 = (unsigned)bf16_bits(z0[2]*mk[2]) | ((unsigned)bf16_bits(z0[3]*mk[3]) << 16);
  unsigned int pb0 = (unsigned)bf16_bits(z1[0]*mk[0]) | ((unsigned)bf16_bits(z1[1]*mk[1]) << 16);
  unsigned int pb1 = (unsigned)bf16_bits(z1[2]*mk[2]) | ((unsigned)bf16_bits(z1[3]*mk[3]) << 16);

  const int p0 = r*H_DIM + row;
  const int p1 = r*H_DIM + 16 + row;
  const int c0 = sb*2 + (q >> 1);      // 16B chunk index along s (0..15)
  const int rem = (q & 1) * 8;
  {
    uint2 v; v.x = pa0; v.y = pa1;
    *reinterpret_cast<uint2*>((char*)dst + (size_t)p0*256 + ((c0 ^ (p0 & 15)) << 4) + rem) = v;
  }
  {
    uint2 v; v.x = pb0; v.y = pb1;
    *reinterpret_cast<uint2*>((char*)dst + (size_t)p1*256 + ((c0 ^ (p1 & 15)) << 4) + rem) = v;
  }
}

// ---------------------------------------------------------------------------
// Kernel 2 (gemm): 256x256 Out1 tile (64 pairs) fused with epilogue.
// 16 waves (1024 thr); LDS 128KB. GEMM1: 4x4 wave grid, 64x64 each (unchanged).
// NEW epilogue: no K-split, 16x16x32 MFMAs; waves (pm 4 x pn 4), each wave
// 16 pairs x 32 t x full K=1024. No deposit/reduce tail (2 fewer barriers,
// -256KB LDS traffic); wT2 streamed from global (4 pm-waves share a stream
// -> L1 reuse).
// ---------------------------------------------------------------------------
__global__ __launch_bounds__(1024, 4) void opm_gemm(
    const bf16* __restrict__ aT, const bf16* __restrict__ bT,
    const bf16* __restrict__ wT2, const float* __restrict__ b_out,
    const float* __restrict__ rnorm, float* __restrict__ out)
{
  __shared__ char smem[131072];

  const int tid  = threadIdx.x;
  const int lane = tid & 63;
  const int wid  = tid >> 6;          // 0..15
  const int l31  = lane & 31;
  const int hf   = lane >> 5;

  // XCD-aware bijective swizzle (1024 % 8 == 0)
  int swz = blockIdx.x;
  swz = (swz & 7)*128 + (swz >> 3);
  const int bx = swz >> 5, by = swz & 31;

  // ---- stage A,B tiles (pre-swizzled global -> linear LDS, 16B async) ----
  {
    const char* gA = (const char*)aT + (size_t)bx*65536;
    const char* gB = (const char*)bT + (size_t)by*65536;
    #pragma unroll
    for (int i = 0; i < 4; ++i) {
      const int base = (i*16 + wid)*1024;
      gload_lds16(gA + base + lane*16, smem + base);
      gload_lds16(gB + base + lane*16, smem + 65536 + base);
    }
  }
  __syncthreads();

  // ---- GEMM1: wave grid 4x4, per-wave 64x64, 32x32x16 MFMAs, K=128 ----
  const int wm = wid >> 2, wn = wid & 3;
  f32x16 acc[2][2];
  #pragma unroll
  for (int mf = 0; mf < 2; ++mf)
    #pragma unroll
    for (int nf = 0; nf < 2; ++nf)
      #pragma unroll
      for (int r = 0; r < 16; ++r) acc[mf][nf][r] = 0.f;

  #pragma unroll
  for (int ks = 0; ks < 8; ++ks) {
    s8v af[2], bfv[2];
    #pragma unroll
    for (int mf = 0; mf < 2; ++mf) {
      const int mm = wm*64 + mf*32 + l31;
      int L = (mm*256 + ks*32 + hf*16) ^ ((mm & 15) << 4);
      af[mf] = *reinterpret_cast<const s8v*>(smem + L);
    }
    #pragma unroll
    for (int nf = 0; nf < 2; ++nf) {
      const int nn = wn*64 + nf*32 + l31;
      int L = (nn*256 + ks*32 + hf*16) ^ ((nn & 15) << 4);
      bfv[nf] = *reinterpret_cast<const s8v*>(smem + 65536 + L);
    }
    #pragma unroll
    for (int mf = 0; mf < 2; ++mf)
      #pragma unroll
      for (int nf = 0; nf < 2; ++nf)
        acc[mf][nf] = __builtin_amdgcn_mfma_f32_32x32x16_bf16(af[mf], bfv[nf], acc[mf][nf], 0, 0, 0);
  }
  __syncthreads();   // all LDS reads of A/B done

  // ---- Oep-write phase (unchanged layout) ----
  // Oep[pair][ce'] bf16; L0 = pair*2048 + ce'*2;
  // physical = L0 ^ (((pair&15)^((L0>>7)&15))<<4)
  #pragma unroll
  for (int mf = 0; mf < 2; ++mf) {
    #pragma unroll
    for (int nf = 0; nf < 2; ++nf) {
      const int pair = (wm*2 + mf)*8 + wn*2 + nf;
      #pragma unroll
      for (int g = 0; g < 4; ++g) {
        const unsigned int lo = (unsigned)bf16_bits(acc[mf][nf][4*g+0]) |
                                ((unsigned)bf16_bits(acc[mf][nf][4*g+1]) << 16);
        const unsigned int hi = (unsigned)bf16_bits(acc[mf][nf][4*g+2]) |
                                ((unsigned)bf16_bits(acc[mf][nf][4*g+3]) << 16);
        const int L0 = pair*2048 + (l31*32 + 8*g + 4*hf)*2;
        const int L  = L0 ^ ((((pair & 15) ^ ((L0 >> 7) & 15))) << 4);
        uint2 v; v.x = lo; v.y = hi;
        *reinterpret_cast<uint2*>(smem + L) = v;
      }
    }
  }
  __syncthreads();

  // ---- epilogue (no K-split): waves (pm = wid>>2, pn = wid&3) ----
  // per wave: pairs pm*16..+15, t = pn*32..+31, K=1024 in 32 ks-steps.
  {
    const int pm = wid >> 2, pn = wid & 3;
    const int l15 = lane & 15;
    const int q4  = lane >> 4;        // 0..3
    const int tA  = pn*32 + l15;
    const int tB  = tA + 16;
    const float bo0 = b_out[tA];
    const float bo1 = b_out[tB];
    f32x4 z0 = {bo0, bo0, bo0, bo0};
    f32x4 z1 = {bo1, bo1, bo1, bo1};

    const int pair = pm*16 + l15;
    const char* wb0 = (const char*)wT2 + (((size_t)(pn*2 + 0)*32)*64 + lane)*16;
    const char* wb1 = (const char*)wT2 + (((size_t)(pn*2 + 1)*32)*64 + lane)*16;

    #pragma unroll 8
    for (int ks = 0; ks < 32; ++ks) {
      int L0 = pair*2048 + ks*64 + q4*16;
      int L  = L0 ^ ((((pair & 15) ^ ((L0 >> 7) & 15))) << 4);
      const s8v a  = *reinterpret_cast<const s8v*>(smem + L);
      const s8v w0 = *reinterpret_cast<const s8v*>(wb0 + ks*1024);
      const s8v w1 = *reinterpret_cast<const s8v*>(wb1 + ks*1024);
      z0 = __builtin_amdgcn_mfma_f32_16x16x32_bf16(a, w0, z0, 0, 0, 0);
      z1 = __builtin_amdgcn_mfma_f32_16x16x32_bf16(a, w1, z1, 0, 0, 0);
    }

    // D: col = l15 (t), row = q4*4 + j (pair offset within pm block)
    #pragma unroll
    for (int j = 0; j < 4; ++j) {
      const int pr = pm*16 + q4*4 + j;
      const int o  = (bx*8 + (pr >> 3))*R_DIM + by*8 + (pr & 7);
      const float rn = rnorm[o];
      out[(size_t)o*CZ + tA] = z0[j] * rn;
      out[(size_t)o*CZ + tB] = z1[j] * rn;
    }
  }
}

// ---------------------------------------------------------------------------
extern "C" void kernel_launch(void* const* d_in, const int* in_sizes, int n_in,
                              void* d_out, int out_size, void* d_ws, size_t ws_size,
                              hipStream_t stream) {
  const float* m_1    = (const float*)d_in[0];
  const float* m_2    = (const float*)d_in[1];
  const float* mask_1 = (const float*)d_in[2];
  const float* mask_2 = (const float*)d_in[3];
  const float* ln1_w  = (const float*)d_in[4];
  const float* ln1_b  = (const float*)d_in[5];
  const float* ln2_w  = (const float*)d_in[6];
  const float* ln2_b  = (const float*)d_in[7];
  const float* w1     = (const float*)d_in[8];
  const float* b1     = (const float*)d_in[9];
  const float* w2     = (const float*)d_in[10];
  const float* b2     = (const float*)d_in[11];
  const float* w_out  = (const float*)d_in[12];
  const float* b_out  = (const float*)d_in[13];
  float* out = (float*)d_out;

  char* ws = (char*)d_ws;
  bf16* aT    = (bf16*)ws;                                  // 2 MB, pre-swizzled
  bf16* bT    = (bf16*)(ws + (2u << 20));                   // 2 MB
  bf16* wT2   = (bf16*)(ws + (4u << 20));                   // 256 KB frag-ordered
  float* rnrm = (float*)(ws + (4u << 20) + (256u << 10));   // 256 KB
  bf16* wF    = (bf16*)(ws + (4u << 20) + (512u << 10));    // 32 KB proj w frags

  opm_prep<<<dim3(322),      dim3(256), 0, stream>>>(w_out, mask_1, mask_2,
      w1, w2, wT2, rnrm, wF);
  opm_proj<<<dim3(2048, 2),  dim3(64),  0, stream>>>(m_1, m_2, ln1_w, ln1_b,
      ln2_w, ln2_b, b1, b2, mask_1, mask_2, wF, aT, bT);
  opm_gemm<<<dim3(1024),     dim3(1024), 0, stream>>>(aT, bT, wT2, b_out, rnrm, out);
}

// Round 14
// 72.536 us; speedup vs baseline: 1.2088x; 1.2088x over previous
//
#include <hip/hip_runtime.h>
#include <hip/hip_bf16.h>

#define S_DIM 128
#define R_DIM 256
#define CM    256
#define H_DIM 32
#define CZ    128

typedef short s8v   __attribute__((ext_vector_type(8)));   // 8 bf16 in 4 VGPRs
typedef float f32x4 __attribute__((ext_vector_type(4)));
typedef float f32x16 __attribute__((ext_vector_type(16)));
using bf16 = __hip_bfloat16;

static __device__ __forceinline__ unsigned short bf16_bits(float f) {
  return __builtin_bit_cast(unsigned short, __float2bfloat16(f));
}

static __device__ __forceinline__ void gload_lds16(const void* g, void* l) {
  __builtin_amdgcn_global_load_lds(
      (const __attribute__((address_space(1))) unsigned int*)g,
      (__attribute__((address_space(3))) unsigned int*)l, 16, 0, 0);
}

// ---------------------------------------------------------------------------
// Kernel 0 (wf, tiny): w1/w2 [256][32] fp32 -> wF bf16 in proj B-frag order.
// Must run before opm_proj (its only consumer).
// ---------------------------------------------------------------------------
__global__ __launch_bounds__(256) void opm_wf(
    const float* __restrict__ w1, const float* __restrict__ w2,
    bf16* __restrict__ wF)
{
  const int mat = blockIdx.x;
  const int tid = threadIdx.x;
  const float* __restrict__ w = mat ? w2 : w1;
  bf16* __restrict__ dst = wF + mat*8192;
  #pragma unroll
  for (int it = 0; it < 4; ++it) {
    const int vid  = it*256 + tid;
    const int nf   = vid >> 9;
    const int ks   = (vid >> 6) & 7;
    const int lane = vid & 63;
    const int h    = nf*16 + (lane & 15);
    unsigned int pk[4];
    #pragma unroll
    for (int ep = 0; ep < 4; ++ep) {
      const int c0 = ks*32 + (lane >> 4)*8 + ep*2;
      unsigned int lo = bf16_bits(w[c0*H_DIM + h]);
      unsigned int hi = bf16_bits(w[(c0 + 1)*H_DIM + h]);
      pk[ep] = lo | (hi << 16);
    }
    uint4 o = {pk[0], pk[1], pk[2], pk[3]};
    *reinterpret_cast<uint4*>((char*)dst + (size_t)vid*16) = o;
  }
}

// ---------------------------------------------------------------------------
// Kernel 1 (proj + gemm-prep merged): grid (3328, 2), 64 threads.
//  x < 2048, y = 0/1 : proj for m1/m2 (round-8 version, unchanged math;
//                      r = x&255, sb = x>>8 in 0..7 -> s <= 127, IN BOUNDS)
//  x >= 2048, y == 0 : prep work consumed only by gemm:
//    xe = x-2048: xe < 256   -> wT2 (round-8 epilogue B-frag order)
//                 xe < 1280  -> rnorm[i][j]
//  x >= 2048, y == 1 : exit
// ---------------------------------------------------------------------------
__global__ __launch_bounds__(64) void opm_proj(
    const float* __restrict__ m1, const float* __restrict__ m2,
    const float* __restrict__ ln1w, const float* __restrict__ ln1b,
    const float* __restrict__ ln2w, const float* __restrict__ ln2b,
    const float* __restrict__ b1, const float* __restrict__ b2,
    const float* __restrict__ mask1, const float* __restrict__ mask2,
    const float* __restrict__ w_out,
    const bf16* __restrict__ wF, bf16* __restrict__ aT, bf16* __restrict__ bT,
    bf16* __restrict__ wT2, float* __restrict__ rnorm)
{
  __shared__ char xn[8192];   // [16 s][256 c] bf16, byte ^ ((s&7)<<4)

  const int lane = threadIdx.x;

  if (blockIdx.x >= 2048) {
    if (blockIdx.y != 0) return;
    const int xe = blockIdx.x - 2048;
    if (xe < 256) {
      // ---- wT2 (round-8 layout): vid = xe*64 + lane, 16384 slots ----
      const int vid  = xe*64 + lane;
      const int ks2  = (vid >> 6) & 63;
      const int tb   = vid >> 12;
      const int t    = tb*32 + (lane & 31);
      const int hf   = lane >> 5;
      unsigned int pk[4];
      #pragma unroll
      for (int ep = 0; ep < 4; ++ep) {
        const int ce0 = ks2*16 + hf*8 + ep*2;
        const int ce1 = ce0 + 1;
        unsigned int v0 = bf16_bits(w_out[((ce0 & 31)*32 + (ce0 >> 5))*CZ + t]);
        unsigned int v1 = bf16_bits(w_out[((ce1 & 31)*32 + (ce1 >> 5))*CZ + t]);
        pk[ep] = v0 | (v1 << 16);
      }
      uint4 o = {pk[0], pk[1], pk[2], pk[3]};
      *reinterpret_cast<uint4*>((char*)wT2 + (size_t)vid*16) = o;
    } else if (xe < 1280) {
      // ---- rnorm ----
      const int idx = xe - 256;
      const int i = idx >> 2;
      const int j = (idx & 3)*64 + lane;
      float acc = 0.f;
      for (int s = 0; s < S_DIM; ++s)
        acc += mask1[(size_t)s*R_DIM + i] * mask2[(size_t)s*R_DIM + j];
      rnorm[i*R_DIM + j] = 1.0f / (acc + 1e-3f);
    }
    return;
  }

  const int mat = blockIdx.y;
  const float* __restrict__ m    = mat ? m2   : m1;
  const float* __restrict__ lnw  = mat ? ln2w : ln1w;
  const float* __restrict__ lnb  = mat ? ln2b : ln1b;
  const float* __restrict__ bias = mat ? b2   : b1;
  const float* __restrict__ mask = mat ? mask2 : mask1;
  const bf16* __restrict__ wf    = wF + mat*8192;
  bf16* __restrict__ dst         = mat ? bT   : aT;

  const int g16  = lane >> 4;      // row-within-pass (= q later)
  const int c16  = lane & 15;      // 16B segment index (= row later)
  const int r    = blockIdx.x & 255;
  const int sb   = blockIdx.x >> 8;   // 0..7 -> s <= 127

  // ---- issue ALL global loads up front ----
  float4 x[4][4];                  // [pass][it]
  #pragma unroll
  for (int p = 0; p < 4; ++p) {
    const int s = sb*16 + p*4 + g16;
    const float4* __restrict__ src =
        reinterpret_cast<const float4*>(m + ((size_t)s*R_DIM + r)*CM);
    #pragma unroll
    for (int it = 0; it < 4; ++it)
      x[p][it] = src[c16 + it*16];
  }
  const float4* __restrict__ lnw4 = reinterpret_cast<const float4*>(lnw);
  const float4* __restrict__ lnb4 = reinterpret_cast<const float4*>(lnb);
  float4 lw[4], lb[4];
  #pragma unroll
  for (int it = 0; it < 4; ++it) {
    lw[it] = lnw4[c16 + it*16];
    lb[it] = lnb4[c16 + it*16];
  }
  float mk[4];
  #pragma unroll
  for (int rr = 0; rr < 4; ++rr)
    mk[rr] = mask[(size_t)(sb*16 + g16*4 + rr)*R_DIM + r];
  const float bv0 = bias[c16];
  const float bv1 = bias[16 + c16];

  // ---- 4 independent sum/sq + shfl-reduce chains ----
  float sum[4], sq[4];
  #pragma unroll
  for (int p = 0; p < 4; ++p) {
    float s0 = 0.f, s1 = 0.f;
    #pragma unroll
    for (int it = 0; it < 4; ++it) {
      const float4 v = x[p][it];
      s0 += v.x + v.y + v.z + v.w;
      s1 += v.x*v.x + v.y*v.y + v.z*v.z + v.w*v.w;
    }
    sum[p] = s0; sq[p] = s1;
  }
  #pragma unroll
  for (int off = 1; off < 16; off <<= 1) {
    #pragma unroll
    for (int p = 0; p < 4; ++p) {
      sum[p] += __shfl_xor(sum[p], off);
      sq[p]  += __shfl_xor(sq[p], off);
    }
  }
  float mu[4], rs[4];
  #pragma unroll
  for (int p = 0; p < 4; ++p) {
    mu[p] = sum[p] * (1.0f/CM);
    rs[p] = rsqrtf(sq[p] * (1.0f/CM) - mu[p]*mu[p] + 1e-5f);
  }

  // ---- ln affine -> bf16 -> LDS ----
  #pragma unroll
  for (int p = 0; p < 4; ++p) {
    const int row = p*4 + g16;
    #pragma unroll
    for (int it = 0; it < 4; ++it) {
      const float v0 = (x[p][it].x - mu[p])*rs[p]*lw[it].x + lb[it].x;
      const float v1 = (x[p][it].y - mu[p])*rs[p]*lw[it].y + lb[it].y;
      const float v2 = (x[p][it].z - mu[p])*rs[p]*lw[it].z + lb[it].z;
      const float v3 = (x[p][it].w - mu[p])*rs[p]*lw[it].w + lb[it].w;
      uint2 pk;
      pk.x = (unsigned)bf16_bits(v0) | ((unsigned)bf16_bits(v1) << 16);
      pk.y = (unsigned)bf16_bits(v2) | ((unsigned)bf16_bits(v3) << 16);
      int off = row*512 + c16*8 + it*128;
      off ^= (row & 7) << 4;
      *reinterpret_cast<uint2*>(xn + off) = pk;
    }
  }
  __syncthreads();

  // ---- MFMA: [16 s x 256 c] @ w[256 c x 32 h] ----
  const int row = c16;
  const int q   = g16;
  f32x4 z0 = {bv0, bv0, bv0, bv0};
  f32x4 z1 = {bv1, bv1, bv1, bv1};
  #pragma unroll
  for (int ks = 0; ks < 8; ++ks) {
    int off = row*512 + ks*64 + q*16;
    off ^= (row & 7) << 4;
    const s8v a  = *reinterpret_cast<const s8v*>(xn + off);
    const s8v w0 = *reinterpret_cast<const s8v*>((const char*)wf + (ks*64 + lane)*16);
    const s8v w1 = *reinterpret_cast<const s8v*>((const char*)wf + ((8 + ks)*64 + lane)*16);
    z0 = __builtin_amdgcn_mfma_f32_16x16x32_bf16(a, w0, z0, 0, 0, 0);
    z1 = __builtin_amdgcn_mfma_f32_16x16x32_bf16(a, w1, z1, 0, 0, 0);
  }

  unsigned int pa0 = (unsigned)bf16_bits(z0[0]*mk[0]) | ((unsigned)bf16_bits(z0[1]*mk[1]) << 16);
  unsigned int pa1 = (unsigned)bf16_bits(z0[2]*mk[2]) | ((unsigned)bf16_bits(z0[3]*mk[3]) << 16);
  unsigned int pb0 = (unsigned)bf16_bits(z1[0]*mk[0]) | ((unsigned)bf16_bits(z1[1]*mk[1]) << 16);
  unsigned int pb1 = (unsigned)bf16_bits(z1[2]*mk[2]) | ((unsigned)bf16_bits(z1[3]*mk[3]) << 16);

  const int p0 = r*H_DIM + row;
  const int p1 = r*H_DIM + 16 + row;
  const int c0 = sb*2 + (q >> 1);      // 16B chunk index along s (0..15)
  const int rem = (q & 1) * 8;
  {
    uint2 v; v.x = pa0; v.y = pa1;
    *reinterpret_cast<uint2*>((char*)dst + (size_t)p0*256 + ((c0 ^ (p0 & 15)) << 4) + rem) = v;
  }
  {
    uint2 v; v.x = pb0; v.y = pb1;
    *reinterpret_cast<uint2*>((char*)dst + (size_t)p1*256 + ((c0 ^ (p1 & 15)) << 4) + rem) = v;
  }
}

// ---------------------------------------------------------------------------
// Kernel 2 (gemm): 256x256 Out1 tile (64 pairs) fused with epilogue.
// EXACT round-8 version (best measured: 49.9 us).
// ---------------------------------------------------------------------------
__global__ __launch_bounds__(1024, 4) void opm_gemm(
    const bf16* __restrict__ aT, const bf16* __restrict__ bT,
    const bf16* __restrict__ wT2, const float* __restrict__ b_out,
    const float* __restrict__ rnorm, float* __restrict__ out)
{
  __shared__ char smem[131072];

  const int tid  = threadIdx.x;
  const int lane = tid & 63;
  const int wid  = tid >> 6;          // 0..15
  const int l31  = lane & 31;
  const int hf   = lane >> 5;

  // XCD-aware bijective swizzle (1024 % 8 == 0)
  int swz = blockIdx.x;
  swz = (swz & 7)*128 + (swz >> 3);
  const int bx = swz >> 5, by = swz & 31;

  // ---- stage A,B tiles (pre-swizzled global -> linear LDS, 16B async) ----
  {
    const char* gA = (const char*)aT + (size_t)bx*65536;
    const char* gB = (const char*)bT + (size_t)by*65536;
    #pragma unroll
    for (int i = 0; i < 4; ++i) {
      const int base = (i*16 + wid)*1024;
      gload_lds16(gA + base + lane*16, smem + base);
      gload_lds16(gB + base + lane*16, smem + 65536 + base);
    }
  }
  __syncthreads();

  // ---- GEMM1: wave grid 4x4, per-wave 64x64, 32x32x16 MFMAs, K=128 ----
  const int wm = wid >> 2, wn = wid & 3;
  f32x16 acc[2][2];
  #pragma unroll
  for (int mf = 0; mf < 2; ++mf)
    #pragma unroll
    for (int nf = 0; nf < 2; ++nf)
      #pragma unroll
      for (int r = 0; r < 16; ++r) acc[mf][nf][r] = 0.f;

  #pragma unroll
  for (int ks = 0; ks < 8; ++ks) {
    s8v af[2], bfv[2];
    #pragma unroll
    for (int mf = 0; mf < 2; ++mf) {
      const int mm = wm*64 + mf*32 + l31;
      int L = (mm*256 + ks*32 + hf*16) ^ ((mm & 15) << 4);
      af[mf] = *reinterpret_cast<const s8v*>(smem + L);
    }
    #pragma unroll
    for (int nf = 0; nf < 2; ++nf) {
      const int nn = wn*64 + nf*32 + l31;
      int L = (nn*256 + ks*32 + hf*16) ^ ((nn & 15) << 4);
      bfv[nf] = *reinterpret_cast<const s8v*>(smem + 65536 + L);
    }
    #pragma unroll
    for (int mf = 0; mf < 2; ++mf)
      #pragma unroll
      for (int nf = 0; nf < 2; ++nf)
        acc[mf][nf] = __builtin_amdgcn_mfma_f32_32x32x16_bf16(af[mf], bfv[nf], acc[mf][nf], 0, 0, 0);
  }
  __syncthreads();   // all LDS reads of A/B done

  // ---- Oep-write phase, interleaved with wT2 VGPR prefetch ----
  const int kq = wm, pn = wn;
  const char* wb = (const char*)wT2 + ((size_t)(pn*64 + kq*16)*64 + lane)*16;
  s8v bwr[16];

  #pragma unroll
  for (int i = 0; i < 8; ++i)
    bwr[i] = *reinterpret_cast<const s8v*>(wb + i*1024);

  #pragma unroll
  for (int nf = 0; nf < 2; ++nf) {
    const int pair = (wm*2 + 0)*8 + wn*2 + nf;
    #pragma unroll
    for (int g = 0; g < 4; ++g) {
      const unsigned int lo = (unsigned)bf16_bits(acc[0][nf][4*g+0]) |
                              ((unsigned)bf16_bits(acc[0][nf][4*g+1]) << 16);
      const unsigned int hi = (unsigned)bf16_bits(acc[0][nf][4*g+2]) |
                              ((unsigned)bf16_bits(acc[0][nf][4*g+3]) << 16);
      const int L0 = pair*2048 + (l31*32 + 8*g + 4*hf)*2;
      const int L  = L0 ^ ((((pair & 15) ^ ((L0 >> 7) & 15))) << 4);
      uint2 v; v.x = lo; v.y = hi;
      *reinterpret_cast<uint2*>(smem + L) = v;
    }
  }

  #pragma unroll
  for (int i = 8; i < 16; ++i)
    bwr[i] = *reinterpret_cast<const s8v*>(wb + i*1024);

  #pragma unroll
  for (int nf = 0; nf < 2; ++nf) {
    const int pair = (wm*2 + 1)*8 + wn*2 + nf;
    #pragma unroll
    for (int g = 0; g < 4; ++g) {
      const unsigned int lo = (unsigned)bf16_bits(acc[1][nf][4*g+0]) |
                              ((unsigned)bf16_bits(acc[1][nf][4*g+1]) << 16);
      const unsigned int hi = (unsigned)bf16_bits(acc[1][nf][4*g+2]) |
                              ((unsigned)bf16_bits(acc[1][nf][4*g+3]) << 16);
      const int L0 = pair*2048 + (l31*32 + 8*g + 4*hf)*2;
      const int L  = L0 ^ ((((pair & 15) ^ ((L0 >> 7) & 15))) << 4);
      uint2 v; v.x = lo; v.y = hi;
      *reinterpret_cast<uint2*>(smem + L) = v;
    }
  }
  __syncthreads();

  // ---- epilogue: wave (kq, pn): k-quarter, t-block pn, 2 pair chains ----
  const int t = pn*32 + l31;
  f32x16 z0, z1;
  {
    const float init = (kq == 0) ? b_out[t] : 0.f;
    #pragma unroll
    for (int r = 0; r < 16; ++r) { z0[r] = init; z1[r] = init; }
  }
  #pragma unroll
  for (int ks = 0; ks < 16; ++ks) {
    const int ks2 = kq*16 + ks;
    {
      const int pair = l31;
      int L0 = pair*2048 + ks2*32 + hf*16;
      int L  = L0 ^ ((((pair & 15) ^ ((L0 >> 7) & 15))) << 4);
      const s8v a = *reinterpret_cast<const s8v*>(smem + L);
      z0 = __builtin_amdgcn_mfma_f32_32x32x16_bf16(a, bwr[ks], z0, 0, 0, 0);
    }
    {
      const int pair = 32 + l31;
      int L0 = pair*2048 + ks2*32 + hf*16;
      int L  = L0 ^ ((((pair & 15) ^ ((L0 >> 7) & 15))) << 4);
      const s8v a = *reinterpret_cast<const s8v*>(smem + L);
      z1 = __builtin_amdgcn_mfma_f32_32x32x16_bf16(a, bwr[ks], z1, 0, 0, 0);
    }
  }
  __syncthreads();   // Oep dead; reuse LDS for partials

  // ---- ALL 16 waves deposit partials at [wid*8192]: z0 then z1 ----
  {
    const int base = wid*8192;
    #pragma unroll
    for (int g = 0; g < 4; ++g) {
      f32x4 v0 = {z0[4*g+0], z0[4*g+1], z0[4*g+2], z0[4*g+3]};
      f32x4 v1 = {z1[4*g+0], z1[4*g+1], z1[4*g+2], z1[4*g+3]};
      *reinterpret_cast<f32x4*>(smem + base +        g*1024 + lane*16) = v0;
      *reinterpret_cast<f32x4*>(smem + base + 4096 + g*1024 + lane*16) = v1;
    }
  }
  __syncthreads();

  // ---- ALL 16 waves reduce+store a slice: chain = kq&1, g-half = kq>>1 ----
  {
    const int chain = kq & 1;
    const int gh    = kq >> 1;
    f32x4 f[2];
    #pragma unroll
    for (int gg = 0; gg < 2; ++gg) {
      const int g = gh*2 + gg;
      f32x4 s = {0.f, 0.f, 0.f, 0.f};
      #pragma unroll
      for (int kk = 0; kk < 4; ++kk) {
        const int base = (kk*4 + pn)*8192 + chain*4096;
        const f32x4 p = *reinterpret_cast<const f32x4*>(smem + base + g*1024 + lane*16);
        #pragma unroll
        for (int j = 0; j < 4; ++j) s[j] += p[j];
      }
      f[gg] = s;
    }
    #pragma unroll
    for (int gg = 0; gg < 2; ++gg) {
      const int g = gh*2 + gg;
      #pragma unroll
      for (int j = 0; j < 4; ++j) {
        const int row  = j + 4*hf + 8*g;
        const int pair = chain*32 + row;
        const int o    = (bx*8 + (pair >> 3))*R_DIM + by*8 + (pair & 7);
        out[(size_t)o*CZ + t] = f[gg][j] * rnorm[o];
      }
    }
  }
}

// ---------------------------------------------------------------------------
extern "C" void kernel_launch(void* const* d_in, const int* in_sizes, int n_in,
                              void* d_out, int out_size, void* d_ws, size_t ws_size,
                              hipStream_t stream) {
  const float* m_1    = (const float*)d_in[0];
  const float* m_2    = (const float*)d_in[1];
  const float* mask_1 = (const float*)d_in[2];
  const float* mask_2 = (const float*)d_in[3];
  const float* ln1_w  = (const float*)d_in[4];
  const float* ln1_b  = (const float*)d_in[5];
  const float* ln2_w  = (const float*)d_in[6];
  const float* ln2_b  = (const float*)d_in[7];
  const float* w1     = (const float*)d_in[8];
  const float* b1     = (const float*)d_in[9];
  const float* w2     = (const float*)d_in[10];
  const float* b2     = (const float*)d_in[11];
  const float* w_out  = (const float*)d_in[12];
  const float* b_out  = (const float*)d_in[13];
  float* out = (float*)d_out;

  char* ws = (char*)d_ws;
  bf16* aT    = (bf16*)ws;                                  // 2 MB, pre-swizzled
  bf16* bT    = (bf16*)(ws + (2u << 20));                   // 2 MB
  bf16* wT2   = (bf16*)(ws + (4u << 20));                   // 256 KB frag-ordered
  float* rnrm = (float*)(ws + (4u << 20) + (256u << 10));   // 256 KB
  bf16* wF    = (bf16*)(ws + (4u << 20) + (512u << 10));    // 32 KB proj w frags

  opm_wf  <<<dim3(2),        dim3(256),  0, stream>>>(w1, w2, wF);
  opm_proj<<<dim3(3328, 2),  dim3(64),   0, stream>>>(m_1, m_2, ln1_w, ln1_b,
      ln2_w, ln2_b, b1, b2, mask_1, mask_2, w_out, wF, aT, bT, wT2, rnrm);
  opm_gemm<<<dim3(1024),     dim3(1024), 0, stream>>>(aT, bT, wT2, b_out, rnrm, out);
}